// Round 5
// baseline (357.218 us; speedup 1.0000x reference)
//
#include <hip/hip_runtime.h>
#include <cstdint>
#include <cstddef>

#define HW (512 * 512)
#define NB 128
#define NPAIR 96
#define THRQ 4.9f            // > ln(128)=4.852: q>THRQ && !mask => bin 0 guaranteed
#define BSCALE 64.0f         // NB/2
#define RB 128               // blocks along x for both big kernels
#define TOTB (RB * 12 * 2)   // hist block count (counter target)

// workspace float/word offsets
#define W_HNEG 0
#define W_HPOS (NPAIR * NB)                  // 12288
#define W_SEEDL (NPAIR * NB * 2)             // 24576
#define W_CNTH (W_SEEDL + NPAIR)             // 24672
#define NZERO (W_CNTH + 1)                   // 24673 words zeroed by reduce_k
#define W_PART 24704                         // part[24][41][RB]
#define W_CSUM (W_PART + 24 * 41 * RB)       // 150656, csum[24][41]

__device__ __forceinline__ float sigmoidf_(float x) {
    return 1.0f / (1.0f + __expf(-x));
}
__device__ __forceinline__ float tanhf_(float x) {
    float e = __expf(2.0f * x);
    return 1.0f - 2.0f / (e + 1.0f);
}
__device__ __forceinline__ float wred(float v) {
#pragma unroll
    for (int o = 32; o > 0; o >>= 1) v += __shfl_down(v, o, 64);
    return v;
}
__device__ __forceinline__ unsigned wredu(unsigned v) {
#pragma unroll
    for (int o = 32; o > 0; o >>= 1) v += __shfl_down(v, o, 64);
    return v;
}

// ---------------------------------------------------------------- pass 1: partial reductions (4 instances/block) + zero hist bufs
// part[(item*2+z)][comp][bx]: comps 0..19 = jj*5+{npx,sum_s0,sum_s0^2,sum_s1,sum_s1^2}
//                             comps 20..39 = jj*5+{cy,cx,ccnt,oy,ox}
//                             comp 40 = seed bg sum (valid for z==0 seg items)
__global__ __launch_bounds__(256) void reduce_k(
    const float* __restrict__ segp, const float* __restrict__ trap,
    const int* __restrict__ inst, const int* __restrict__ cen,
    const float* __restrict__ off, float* __restrict__ ws)
{
    __shared__ float wavepart[4][21];
    __shared__ float centacc[20];
    int item = blockIdx.y, z = blockIdx.z;
    bool isseg = item < 8;
    int ii = isseg ? item : item - 8;
    int bx = blockIdx.x, tid = threadIdx.x;

    // cooperative zero of hneg/hpos/seedl/counter (consumed only by hist_k, launched after)
    {
        int gb = (((z * 12 + item) * RB) + bx) * 9 + tid;
        if (tid < 9 && gb < NZERO) ws[gb] = 0.0f;
    }
    if (tid < 20) centacc[tid] = 0.0f;
    __syncthreads();

    const float* pb = isseg ? segp + (size_t)item * 5 * HW
                            : trap + (size_t)ii * 4 * HW;
    const int* ib = inst + (size_t)ii * HW;
    const int* cb = cen + (size_t)ii * HW;
    const float* ob = off + (size_t)ii * 2 * HW;
    bool doseed = isseg && (z == 0);
    int jlo = z * 4;   // this block handles instance ids jlo+1 .. jlo+4

    float npx[4], a0[4], q0[4], a1[4], q1[4];
#pragma unroll
    for (int j = 0; j < 4; j++) { npx[j]=0.f; a0[j]=0.f; q0[j]=0.f; a1[j]=0.f; q1[j]=0.f; }
    float sacc = 0.f;

    int base = bx * 2048;
#pragma unroll
    for (int it = 0; it < 2; ++it) {
        int idx = base + (it * 256 + tid) * 4;
        int4 v4 = *(const int4*)&ib[idx];
        int4 c4 = *(const int4*)&cb[idx];
        float4 x2 = *(const float4*)&pb[2 * HW + idx];
        float4 x3 = *(const float4*)&pb[3 * HW + idx];
        float4 x4v = make_float4(0.f, 0.f, 0.f, 0.f);
        if (doseed) x4v = *(const float4*)&pb[4 * HW + idx];
        const int vs[4] = { v4.x, v4.y, v4.z, v4.w };
        const int cs[4] = { c4.x, c4.y, c4.z, c4.w };
        const float s2s[4] = { x2.x, x2.y, x2.z, x2.w };
        const float s3s[4] = { x3.x, x3.y, x3.z, x3.w };
        const float s4s[4] = { x4v.x, x4v.y, x4v.z, x4v.w };
#pragma unroll
        for (int c = 0; c < 4; c++) {
            int v = vs[c];
            if (doseed && v == 0) { float sd = sigmoidf_(s4s[c]); sacc += sd * sd; }
            if (v > jlo && v <= jlo + 4) {
                float s0 = sigmoidf_(s2s[c]);
                float s1 = sigmoidf_(s3s[c]);
                float s00 = s0 * s0, s11 = s1 * s1;
#pragma unroll
                for (int jj = 0; jj < 4; jj++) {
                    float f = (v == jlo + jj + 1) ? 1.0f : 0.0f;
                    npx[jj] += f;
                    a0[jj] += f * s0; q0[jj] += f * s00;
                    a1[jj] += f * s1; q1[jj] += f * s11;
                }
                if (cs[c] != 0) {
                    int idxc = idx + c;
                    int cb5 = (v - 1 - jlo) * 5;
                    int y = idxc >> 9, x = idxc & 511;
                    atomicAdd(&centacc[cb5 + 0], (float)y * (1.0f / 511.0f));
                    atomicAdd(&centacc[cb5 + 1], (float)x * (1.0f / 511.0f));
                    atomicAdd(&centacc[cb5 + 2], 1.0f);
                    if (!isseg) {
                        atomicAdd(&centacc[cb5 + 3], ob[idxc]);
                        atomicAdd(&centacc[cb5 + 4], ob[HW + idxc]);
                    }
                }
            }
        }
    }
    int lane = tid & 63, wave = tid >> 6;
#pragma unroll
    for (int jj = 0; jj < 4; jj++) {
        float r0 = wred(npx[jj]), r1 = wred(a0[jj]), r2 = wred(q0[jj]);
        float r3 = wred(a1[jj]), r4 = wred(q1[jj]);
        if (lane == 0) {
            wavepart[wave][jj * 5 + 0] = r0; wavepart[wave][jj * 5 + 1] = r1;
            wavepart[wave][jj * 5 + 2] = r2; wavepart[wave][jj * 5 + 3] = r3;
            wavepart[wave][jj * 5 + 4] = r4;
        }
    }
    {
        float rs = wred(sacc);
        if (lane == 0) wavepart[wave][20] = rs;
    }
    __syncthreads();
    float* pit = ws + W_PART + (size_t)(item * 2 + z) * 41 * RB;
    if (tid < 20) {
        pit[tid * RB + bx] = wavepart[0][tid] + wavepart[1][tid] + wavepart[2][tid] + wavepart[3][tid];
    } else if (tid < 40) {
        pit[tid * RB + bx] = centacc[tid - 20];
    } else if (tid == 40) {
        pit[40 * RB + bx] = wavepart[0][20] + wavepart[1][20] + wavepart[2][20] + wavepart[3][20];
    }
}

// ---------------------------------------------------------------- pass 2: histogram (4 instances/block) + last-block scan/combine
__global__ __launch_bounds__(256) void hist_k(
    const float* __restrict__ segp, const float* __restrict__ trap,
    const int* __restrict__ inst, float* __restrict__ ws,
    float* __restrict__ out)
{
    __shared__ unsigned hh[4 * NB + 4];    // packed hist; tail 4 = per-pair seed sums (float)
    __shared__ float csh[41];
    __shared__ float prm[4][4];            // cy, cx, s0, s1
    __shared__ float fin[NPAIR * 4 + 8];
    __shared__ unsigned lastFlag;
    int item = blockIdx.y, z = blockIdx.z;
    bool isseg = item < 8;
    int ii = isseg ? item : item - 8;
    int bx = blockIdx.x, tid = threadIdx.x;
    int pairBase = (isseg ? 0 : 64) + ii * 8 + z * 4;
    int jlo = z * 4;

    unsigned* wsu = (unsigned*)ws;
    unsigned* hneg = wsu + W_HNEG;
    unsigned* hpos = wsu + W_HPOS;
    float* seedl = ws + W_SEEDL;
    unsigned* cnth = wsu + W_CNTH;

    for (int i = tid; i < 4 * NB + 4; i += 256) hh[i] = 0u;
    if (tid < 41) csh[tid] = 0.0f;
    __syncthreads();
    // derive this (item,z)'s 41 comp sums from the partials
    const float* pit = ws + W_PART + (size_t)(item * 2 + z) * 41 * RB;
    if (tid < 164) {
        int comp = tid >> 2, q = tid & 3;
        const float* p = pit + comp * RB + q * 32;
        float s = 0.f;
#pragma unroll 8
        for (int i = 0; i < 32; i++) s += p[i];
        atomicAdd(&csh[comp], s);
    }
    __syncthreads();
    if (tid < 4) {
        int jj = tid;
        float np = fmaxf(csh[jj * 5], 1.0f);
        float cy = csh[20 + jj * 5], cx = csh[20 + jj * 5 + 1];
        if (!isseg) {
            cy -= csh[20 + jj * 5 + 3] * (1.0f / 256.0f);
            cx -= csh[20 + jj * 5 + 4] * (1.0f / 256.0f);
        }
        prm[jj][0] = cy;
        prm[jj][1] = cx;
        prm[jj][2] = __expf(10.0f * csh[jj * 5 + 1] / np);
        prm[jj][3] = __expf(10.0f * csh[jj * 5 + 3] / np);
    }
    if (bx == 0 && tid < 41) ws[W_CSUM + (item * 2 + z) * 41 + tid] = csh[tid];
    __syncthreads();

    float cyR[4], cxR[4], s0R[4], s1R[4];
#pragma unroll
    for (int jj = 0; jj < 4; jj++) {
        cyR[jj] = prm[jj][0]; cxR[jj] = prm[jj][1];
        s0R[jj] = prm[jj][2]; s1R[jj] = prm[jj][3];
    }
    const float* pb = isseg ? segp + (size_t)item * 5 * HW
                            : trap + (size_t)ii * 4 * HW;
    const int* ib = inst + (size_t)ii * HW;

    unsigned cnt0[4];
#pragma unroll
    for (int jj = 0; jj < 4; jj++) cnt0[jj] = 0u;

    int base = bx * 2048;
#pragma unroll
    for (int it = 0; it < 2; ++it) {
        int idx = base + (it * 256 + tid) * 4;
        int4 v4 = *(const int4*)&ib[idx];
        float4 f0 = *(const float4*)&pb[idx];
        float4 f1 = *(const float4*)&pb[HW + idx];
        const int vv[4] = { v4.x, v4.y, v4.z, v4.w };
        const float p0s[4] = { f0.x, f0.y, f0.z, f0.w };
        const float p1s[4] = { f1.x, f1.y, f1.z, f1.w };
#pragma unroll
        for (int c = 0; c < 4; c++) {
            int idxc = idx + c;
            int v = vv[c];
            int y = idxc >> 9, x = idxc & 511;
            float ym = (float)y * (1.0f / 511.0f);
            float xm = (float)x * (1.0f / 511.0f);
            float t0 = tanhf_(p0s[c]), t1 = tanhf_(p1s[c]);
            float e0 = isseg ? (t0 + ym) : (ym - t0);
            float e1 = isseg ? (t1 + xm) : (xm - t1);
            unsigned sbits = 0u;
#pragma unroll
            for (int jj = 0; jj < 4; jj++) {
                float d0 = e0 - cyR[jj], d1 = e1 - cxR[jj];
                float q = fmaf(d0 * d0, s0R[jj], d1 * d1 * s1R[jj]);
                bool m = (v == jlo + jj + 1);
                bool slow = m || (q <= THRQ);
                sbits |= (slow ? 1u : 0u) << jj;
                cnt0[jj] += slow ? 0u : 1u;     // far-field => bin 0 negative
            }
            while (sbits) {
                int jj = __ffs(sbits) - 1;
                sbits &= sbits - 1u;
                float d0 = e0 - prm[jj][0], d1 = e1 - prm[jj][1];
                float q = fmaf(d0 * d0, prm[jj][2], d1 * d1 * prm[jj][3]);
                float dd = __expf(-q);
                bool m = (v == jlo + jj + 1);
                float e = m ? fmaf(-2.0f, dd, 2.0f) : 2.0f * dd;
                int bin = (int)(e * BSCALE);
                if (bin > NB - 1) bin = NB - 1;
                atomicAdd(&hh[jj * NB + bin], m ? 0x10000u : 1u);
                if (m && isseg) {
                    float sd = sigmoidf_(pb[4 * HW + idxc]);
                    float df = sd - dd;
                    atomicAdd((float*)&hh[4 * NB + jj], df * df);
                }
            }
        }
    }
    int lane = tid & 63;
#pragma unroll
    for (int jj = 0; jj < 4; jj++) {
        unsigned r = wredu(cnt0[jj]);
        if (lane == 0 && r) atomicAdd(&hh[jj * NB], r);
    }
    __syncthreads();

    // flush packed LDS hist -> global
#pragma unroll
    for (int jj = 0; jj < 4; jj++) {
        size_t gb = (size_t)(pairBase + jj) * NB;
        for (int i = tid; i < NB; i += 256) {
            unsigned hv = hh[jj * NB + i];
            if (hv) {
                unsigned n = hv & 0xFFFFu, p = hv >> 16;
                if (n) atomicAdd(&hneg[gb + i], n);
                if (p) atomicAdd(&hpos[gb + i], p);
            }
        }
    }
    if (isseg && tid < 4) {
        float sv = __uint_as_float(hh[4 * NB + tid]);
        if (sv != 0.0f) atomicAdd(&seedl[pairBase + tid], sv);
    }
    __syncthreads();
    __threadfence();
    if (tid == 0) lastFlag = (atomicAdd(cnth, 1u) == (unsigned)(TOTB - 1)) ? 1u : 0u;
    __syncthreads();
    if (!lastFlag) return;
    __threadfence();   // acquire: see all blocks' atomics/stores

    // ---- last block: 96-pair descending scan + combine ----
    int wave = tid >> 6;
    volatile const unsigned* vhn = (volatile const unsigned*)(wsu + W_HNEG);
    volatile const unsigned* vhp = (volatile const unsigned*)(wsu + W_HPOS);
    volatile const float* csv = (volatile const float*)(ws + W_CSUM);
    volatile const float* sdv = (volatile const float*)(ws + W_SEEDL);

    for (int p = wave; p < NPAIR; p += 4) {
        int item12 = (p < 64) ? (p >> 3) : (8 + ((p - 64) >> 3));
        int j = p & 7;
        int zz = j >> 2, jj = j & 3;
        float val = 0.f;
        if (lane < 10) {
            int comp = (lane < 5) ? (jj * 5 + lane) : (20 + jj * 5 + (lane - 5));
            val = csv[(item12 * 2 + zz) * 41 + comp];
        }
        float r0 = __shfl(val, 0, 64), r1 = __shfl(val, 1, 64), r2 = __shfl(val, 2, 64);
        float r3 = __shfl(val, 3, 64), r4 = __shfl(val, 4, 64);
        float c0 = __shfl(val, 5, 64), c1 = __shfl(val, 6, 64), c2 = __shfl(val, 7, 64);
        float c3 = __shfl(val, 8, 64), c4 = __shfl(val, 9, 64);

        unsigned hnv[2], hpv[2];
        float ck = 0.f, cp = 0.f;
#pragma unroll
        for (int i = 0; i < 2; i++) {
            int bn = NB - 1 - (lane * 2 + i);
            unsigned a = vhn[(size_t)p * NB + bn], b = vhp[(size_t)p * NB + bn];
            hnv[i] = a; hpv[i] = b;
            ck += (float)(a + b); cp += (float)b;
        }
        float ik = ck, ip = cp;
#pragma unroll
        for (int o = 1; o < 64; o <<= 1) {
            float nk = __shfl_up(ik, o, 64), np2 = __shfl_up(ip, o, 64);
            if (lane >= o) { ik += nk; ip += np2; }
        }
        float P = __shfl(ip, 63, 64);
        float k = ik - ck, pp = ip - cp;
        float acc = 0.f;
#pragma unroll
        for (int i = 0; i < 2; i++) {
            float cn = (float)hnv[i], cpp = (float)hpv[i];
            float c = cn + cpp;
            if (c > 0.f) {
                float Jb = (k > 0.f) ? (1.0f - (P - pp) / (P + k - pp)) : 0.0f;
                k += c; pp += cpp;
                float Ja = 1.0f - (P - pp) / (P + k - pp);
                int bn = NB - 1 - (lane * 2 + i);
                acc += ((float)bn + 0.5f) * (2.0f / NB) * (Ja - Jb);
            }
        }
        acc = wred(acc);
        if (lane == 0) {
            float np = fmaxf(r0, 1.0f);
            float v0 = fmaxf(r2 - r1 * r1 / np, 0.0f);
            float v1 = fmaxf(r4 - r3 * r3 / np, 0.0f);
            float valid, varl;
            if (p < 64) {
                varl = (v0 + v1) / (2.0f * np);
                valid = (c2 > 0.5f && c2 < 1.5f) ? 1.0f : 0.0f;
            } else {
                varl = v0 + v1;
                float gy = c0 - c3 * (1.0f / 256.0f);
                float gx = c1 - c4 * (1.0f / 256.0f);
                valid = (c2 > 0.5f && c2 < 1.5f &&
                         gy >= 0.0f && gy <= 1.0f && gx >= 0.0f && gx <= 1.0f) ? 1.0f : 0.0f;
            }
            fin[p * 4 + 0] = acc; fin[p * 4 + 1] = valid;
            fin[p * 4 + 2] = varl; fin[p * 4 + 3] = sdv[p];
        }
    }
    if (tid < 8) fin[NPAIR * 4 + tid] = csv[(tid * 2 + 0) * 41 + 40];
    __syncthreads();
    if (tid == 0) {
        double total = 0.0;
        for (int b = 0; b < 8; b++) {
            double s = 0.0, sl = 0.0;
            for (int jj2 = 0; jj2 < 8; jj2++) {
                int pr = b * 8 + jj2;
                double v = fin[pr * 4 + 1];
                s += v * ((double)fin[pr * 4 + 0] + 10.0 * (double)fin[pr * 4 + 2]);
                sl += v * (double)fin[pr * 4 + 3];
            }
            total += s + ((double)fin[NPAIR * 4 + b] + sl) / (double)HW;
        }
        for (int tt = 0; tt < 4; tt++) {
            double tl = 0.0, vl = 0.0, cnt = 0.0;
            for (int jj2 = 0; jj2 < 8; jj2++) {
                int pr = 64 + tt * 8 + jj2;
                double v = fin[pr * 4 + 1];
                tl += v * (double)fin[pr * 4 + 0];
                vl += v * (double)fin[pr * 4 + 2];
                cnt += v;
            }
            if (cnt < 1.0) cnt = 1.0;
            total += tl / cnt + 10.0 * vl / cnt;
        }
        *out = (float)total;
    }
}

// ---------------------------------------------------------------- launch
extern "C" void kernel_launch(void* const* d_in, const int* in_sizes, int n_in,
                              void* d_out, int out_size, void* d_ws, size_t ws_size,
                              hipStream_t stream)
{
    const float* segp = (const float*)d_in[0];   // [8,5,512,512] f32
    const float* trap = (const float*)d_in[1];   // [4,4,512,512] f32
    const int* inst   = (const int*)d_in[2];     // [8,512,512] i32
    // d_in[3] = labels: unused (label == (inst > 0) by construction)
    const int* cen    = (const int*)d_in[4];     // [8,512,512] i32 (bool)
    const float* off  = (const float*)d_in[5];   // [4,2,512,512] f32
    float* out = (float*)d_out;
    float* ws = (float*)d_ws;

    reduce_k<<<dim3(RB, 12, 2), 256, 0, stream>>>(segp, trap, inst, cen, off, ws);
    hist_k<<<dim3(RB, 12, 2), 256, 0, stream>>>(segp, trap, inst, ws, out);
}

// Round 6
// 74.340 us; speedup vs baseline: 4.8052x; 4.8052x over previous
//
#include <hip/hip_runtime.h>
#include <cstdint>
#include <cstddef>

#define HW (512 * 512)
#define NB 128
#define NPAIR 96
#define THRQ 4.9f            // > ln(128)=4.852: q>THRQ && !mask => bin 0 guaranteed
#define BSCALE 64.0f         // NB/2
#define RB 128               // blocks along x for both big kernels

// workspace float/word offsets
#define W_HNEG 0
#define W_HPOS (NPAIR * NB)                  // 12288
#define W_SEEDL (NPAIR * NB * 2)             // 24576
#define W_CNT (W_SEEDL + NPAIR)              // 24672 (used by scanfin_k)
#define NZERO (W_CNT + 1)                    // 24673 words zeroed by reduce_k
#define W_PART 24704                         // part[24][41][RB]
#define W_CSUM (W_PART + 24 * 41 * RB)       // csum[24][41]
#define W_POUT (W_CSUM + 24 * 41)            // pairout[96][4]

__device__ __forceinline__ float sigmoidf_(float x) {
    return 1.0f / (1.0f + __expf(-x));
}
__device__ __forceinline__ float tanhf_(float x) {
    float e = __expf(2.0f * x);
    return 1.0f - 2.0f / (e + 1.0f);
}
__device__ __forceinline__ float wred(float v) {
#pragma unroll
    for (int o = 32; o > 0; o >>= 1) v += __shfl_down(v, o, 64);
    return v;
}
__device__ __forceinline__ unsigned wredu(unsigned v) {
#pragma unroll
    for (int o = 32; o > 0; o >>= 1) v += __shfl_down(v, o, 64);
    return v;
}

// ---------------------------------------------------------------- pass 1: partial reductions (4 instances/block) + zero hist bufs
// part[(item*2+z)][comp][bx]: comps 0..19 = jj*5+{npx,sum_s0,sum_s0^2,sum_s1,sum_s1^2}
//                             comps 20..39 = jj*5+{cy,cx,ccnt,oy,ox}
//                             comp 40 = seed bg sum (valid for z==0 seg items)
__global__ __launch_bounds__(256) void reduce_k(
    const float* __restrict__ segp, const float* __restrict__ trap,
    const int* __restrict__ inst, const int* __restrict__ cen,
    const float* __restrict__ off, float* __restrict__ ws)
{
    __shared__ float wavepart[4][21];
    __shared__ float centacc[20];
    int item = blockIdx.y, z = blockIdx.z;
    bool isseg = item < 8;
    int ii = isseg ? item : item - 8;
    int bx = blockIdx.x, tid = threadIdx.x;

    // cooperative zero of hneg/hpos/seedl/counter (consumed only by later kernels)
    {
        int gb = (((z * 12 + item) * RB) + bx) * 9 + tid;
        if (tid < 9 && gb < NZERO) ws[gb] = 0.0f;
    }
    if (tid < 20) centacc[tid] = 0.0f;
    __syncthreads();

    const float* pb = isseg ? segp + (size_t)item * 5 * HW
                            : trap + (size_t)ii * 4 * HW;
    const int* ib = inst + (size_t)ii * HW;
    const int* cb = cen + (size_t)ii * HW;
    const float* ob = off + (size_t)ii * 2 * HW;
    bool doseed = isseg && (z == 0);
    int jlo = z * 4;   // this block handles instance ids jlo+1 .. jlo+4

    float npx[4], a0[4], q0[4], a1[4], q1[4];
#pragma unroll
    for (int j = 0; j < 4; j++) { npx[j]=0.f; a0[j]=0.f; q0[j]=0.f; a1[j]=0.f; q1[j]=0.f; }
    float sacc = 0.f;

    int base = bx * 2048;
#pragma unroll
    for (int it = 0; it < 2; ++it) {
        int idx = base + (it * 256 + tid) * 4;
        int4 v4 = *(const int4*)&ib[idx];
        int4 c4 = *(const int4*)&cb[idx];
        float4 x2 = *(const float4*)&pb[2 * HW + idx];
        float4 x3 = *(const float4*)&pb[3 * HW + idx];
        float4 x4v = make_float4(0.f, 0.f, 0.f, 0.f);
        if (doseed) x4v = *(const float4*)&pb[4 * HW + idx];
        const int vs[4] = { v4.x, v4.y, v4.z, v4.w };
        const int cs[4] = { c4.x, c4.y, c4.z, c4.w };
        const float s2s[4] = { x2.x, x2.y, x2.z, x2.w };
        const float s3s[4] = { x3.x, x3.y, x3.z, x3.w };
        const float s4s[4] = { x4v.x, x4v.y, x4v.z, x4v.w };
#pragma unroll
        for (int c = 0; c < 4; c++) {
            int v = vs[c];
            if (doseed && v == 0) { float sd = sigmoidf_(s4s[c]); sacc += sd * sd; }
            if (v > jlo && v <= jlo + 4) {
                float s0 = sigmoidf_(s2s[c]);
                float s1 = sigmoidf_(s3s[c]);
                float s00 = s0 * s0, s11 = s1 * s1;
#pragma unroll
                for (int jj = 0; jj < 4; jj++) {
                    float f = (v == jlo + jj + 1) ? 1.0f : 0.0f;
                    npx[jj] += f;
                    a0[jj] += f * s0; q0[jj] += f * s00;
                    a1[jj] += f * s1; q1[jj] += f * s11;
                }
                if (cs[c] != 0) {
                    int idxc = idx + c;
                    int cb5 = (v - 1 - jlo) * 5;
                    int y = idxc >> 9, x = idxc & 511;
                    atomicAdd(&centacc[cb5 + 0], (float)y * (1.0f / 511.0f));
                    atomicAdd(&centacc[cb5 + 1], (float)x * (1.0f / 511.0f));
                    atomicAdd(&centacc[cb5 + 2], 1.0f);
                    if (!isseg) {
                        atomicAdd(&centacc[cb5 + 3], ob[idxc]);
                        atomicAdd(&centacc[cb5 + 4], ob[HW + idxc]);
                    }
                }
            }
        }
    }
    int lane = tid & 63, wave = tid >> 6;
#pragma unroll
    for (int jj = 0; jj < 4; jj++) {
        float r0 = wred(npx[jj]), r1 = wred(a0[jj]), r2 = wred(q0[jj]);
        float r3 = wred(a1[jj]), r4 = wred(q1[jj]);
        if (lane == 0) {
            wavepart[wave][jj * 5 + 0] = r0; wavepart[wave][jj * 5 + 1] = r1;
            wavepart[wave][jj * 5 + 2] = r2; wavepart[wave][jj * 5 + 3] = r3;
            wavepart[wave][jj * 5 + 4] = r4;
        }
    }
    {
        float rs = wred(sacc);
        if (lane == 0) wavepart[wave][20] = rs;
    }
    __syncthreads();
    float* pit = ws + W_PART + (size_t)(item * 2 + z) * 41 * RB;
    if (tid < 20) {
        pit[tid * RB + bx] = wavepart[0][tid] + wavepart[1][tid] + wavepart[2][tid] + wavepart[3][tid];
    } else if (tid < 40) {
        pit[tid * RB + bx] = centacc[tid - 20];
    } else if (tid == 40) {
        pit[40 * RB + bx] = wavepart[0][20] + wavepart[1][20] + wavepart[2][20] + wavepart[3][20];
    }
}

// ---------------------------------------------------------------- pass 2: histogram (4 instances/block), plain flush, NO fences
__global__ __launch_bounds__(256) void hist_k(
    const float* __restrict__ segp, const float* __restrict__ trap,
    const int* __restrict__ inst, float* __restrict__ ws)
{
    __shared__ unsigned hh[4 * NB + 4];    // packed hist; tail 4 = per-pair seed sums (float)
    __shared__ float csh[41];
    __shared__ float prm[4][4];            // cy, cx, s0, s1
    int item = blockIdx.y, z = blockIdx.z;
    bool isseg = item < 8;
    int ii = isseg ? item : item - 8;
    int bx = blockIdx.x, tid = threadIdx.x;
    int pairBase = (isseg ? 0 : 64) + ii * 8 + z * 4;
    int jlo = z * 4;

    unsigned* wsu = (unsigned*)ws;
    unsigned* hneg = wsu + W_HNEG;
    unsigned* hpos = wsu + W_HPOS;
    float* seedl = ws + W_SEEDL;

    for (int i = tid; i < 4 * NB + 4; i += 256) hh[i] = 0u;
    if (tid < 41) csh[tid] = 0.0f;
    __syncthreads();
    // derive this (item,z)'s 41 comp sums from the partials
    const float* pit = ws + W_PART + (size_t)(item * 2 + z) * 41 * RB;
    if (tid < 164) {
        int comp = tid >> 2, q = tid & 3;
        const float* p = pit + comp * RB + q * 32;
        float s = 0.f;
#pragma unroll 8
        for (int i = 0; i < 32; i++) s += p[i];
        atomicAdd(&csh[comp], s);
    }
    __syncthreads();
    if (tid < 4) {
        int jj = tid;
        float np = fmaxf(csh[jj * 5], 1.0f);
        float cy = csh[20 + jj * 5], cx = csh[20 + jj * 5 + 1];
        if (!isseg) {
            cy -= csh[20 + jj * 5 + 3] * (1.0f / 256.0f);
            cx -= csh[20 + jj * 5 + 4] * (1.0f / 256.0f);
        }
        prm[jj][0] = cy;
        prm[jj][1] = cx;
        prm[jj][2] = __expf(10.0f * csh[jj * 5 + 1] / np);
        prm[jj][3] = __expf(10.0f * csh[jj * 5 + 3] / np);
    }
    if (bx == 0 && tid < 41) ws[W_CSUM + (item * 2 + z) * 41 + tid] = csh[tid];
    __syncthreads();

    float cyR[4], cxR[4], s0R[4], s1R[4];
#pragma unroll
    for (int jj = 0; jj < 4; jj++) {
        cyR[jj] = prm[jj][0]; cxR[jj] = prm[jj][1];
        s0R[jj] = prm[jj][2]; s1R[jj] = prm[jj][3];
    }
    const float* pb = isseg ? segp + (size_t)item * 5 * HW
                            : trap + (size_t)ii * 4 * HW;
    const int* ib = inst + (size_t)ii * HW;

    unsigned cnt0[4];
#pragma unroll
    for (int jj = 0; jj < 4; jj++) cnt0[jj] = 0u;

    int base = bx * 2048;
#pragma unroll
    for (int it = 0; it < 2; ++it) {
        int idx = base + (it * 256 + tid) * 4;
        int4 v4 = *(const int4*)&ib[idx];
        float4 f0 = *(const float4*)&pb[idx];
        float4 f1 = *(const float4*)&pb[HW + idx];
        const int vv[4] = { v4.x, v4.y, v4.z, v4.w };
        const float p0s[4] = { f0.x, f0.y, f0.z, f0.w };
        const float p1s[4] = { f1.x, f1.y, f1.z, f1.w };
#pragma unroll
        for (int c = 0; c < 4; c++) {
            int idxc = idx + c;
            int v = vv[c];
            int y = idxc >> 9, x = idxc & 511;
            float ym = (float)y * (1.0f / 511.0f);
            float xm = (float)x * (1.0f / 511.0f);
            float t0 = tanhf_(p0s[c]), t1 = tanhf_(p1s[c]);
            float e0 = isseg ? (t0 + ym) : (ym - t0);
            float e1 = isseg ? (t1 + xm) : (xm - t1);
            unsigned sbits = 0u;
#pragma unroll
            for (int jj = 0; jj < 4; jj++) {
                float d0 = e0 - cyR[jj], d1 = e1 - cxR[jj];
                float q = fmaf(d0 * d0, s0R[jj], d1 * d1 * s1R[jj]);
                bool m = (v == jlo + jj + 1);
                bool slow = m || (q <= THRQ);
                sbits |= (slow ? 1u : 0u) << jj;
                cnt0[jj] += slow ? 0u : 1u;     // far-field => bin 0 negative
            }
            while (sbits) {
                int jj = __ffs(sbits) - 1;
                sbits &= sbits - 1u;
                float d0 = e0 - prm[jj][0], d1 = e1 - prm[jj][1];
                float q = fmaf(d0 * d0, prm[jj][2], d1 * d1 * prm[jj][3]);
                float dd = __expf(-q);
                bool m = (v == jlo + jj + 1);
                float e = m ? fmaf(-2.0f, dd, 2.0f) : 2.0f * dd;
                int bin = (int)(e * BSCALE);
                if (bin > NB - 1) bin = NB - 1;
                atomicAdd(&hh[jj * NB + bin], m ? 0x10000u : 1u);
                if (m && isseg) {
                    float sd = sigmoidf_(pb[4 * HW + idxc]);
                    float df = sd - dd;
                    atomicAdd((float*)&hh[4 * NB + jj], df * df);
                }
            }
        }
    }
    int lane = tid & 63;
#pragma unroll
    for (int jj = 0; jj < 4; jj++) {
        unsigned r = wredu(cnt0[jj]);
        if (lane == 0 && r) atomicAdd(&hh[jj * NB], r);
    }
    __syncthreads();

    // flush packed LDS hist -> global
#pragma unroll
    for (int jj = 0; jj < 4; jj++) {
        size_t gb = (size_t)(pairBase + jj) * NB;
        for (int i = tid; i < NB; i += 256) {
            unsigned hv = hh[jj * NB + i];
            if (hv) {
                unsigned n = hv & 0xFFFFu, p = hv >> 16;
                if (n) atomicAdd(&hneg[gb + i], n);
                if (p) atomicAdd(&hpos[gb + i], p);
            }
        }
    }
    if (isseg && tid < 4) {
        float sv = __uint_as_float(hh[4 * NB + tid]);
        if (sv != 0.0f) atomicAdd(&seedl[pairBase + tid], sv);
    }
}

// ---------------------------------------------------------------- pass 3: scan + per-pair params + counter-elected combine
__global__ __launch_bounds__(64) void scanfin_k(
    float* __restrict__ ws, float* __restrict__ out)
{
    __shared__ float fin[NPAIR * 4 + 8];
    int p = blockIdx.x;
    int lane = threadIdx.x;
    unsigned* wsu = (unsigned*)ws;
    const unsigned* hneg = wsu + W_HNEG;
    const unsigned* hpos = wsu + W_HPOS;
    unsigned* cntr = wsu + W_CNT;

    int item12 = (p < 64) ? (p >> 3) : (8 + ((p - 64) >> 3));
    int j = p & 7;
    int zz = j >> 2, jj = j & 3;
    const float* cs = ws + W_CSUM + (item12 * 2 + zz) * 41;
    float val = 0.f;
    if (lane < 10) {
        int comp = (lane < 5) ? (jj * 5 + lane) : (20 + jj * 5 + (lane - 5));
        val = cs[comp];
    }
    float r0 = __shfl(val, 0, 64), r1 = __shfl(val, 1, 64), r2 = __shfl(val, 2, 64);
    float r3 = __shfl(val, 3, 64), r4 = __shfl(val, 4, 64);
    float c0 = __shfl(val, 5, 64), c1 = __shfl(val, 6, 64), c2 = __shfl(val, 7, 64);
    float c3 = __shfl(val, 8, 64), c4 = __shfl(val, 9, 64);

    // descending-bin lovasz scan (NB=128: 2 bins/lane)
    const unsigned* hn = hneg + (size_t)p * NB;
    const unsigned* hp = hpos + (size_t)p * NB;
    unsigned hnv[2], hpv[2];
    float ck = 0.f, cp = 0.f;
#pragma unroll
    for (int i = 0; i < 2; i++) {
        int bn = NB - 1 - (lane * 2 + i);
        unsigned a = hn[bn], b = hp[bn];
        hnv[i] = a; hpv[i] = b;
        ck += (float)(a + b); cp += (float)b;
    }
    float ik = ck, ip = cp;
#pragma unroll
    for (int o = 1; o < 64; o <<= 1) {
        float nk = __shfl_up(ik, o, 64), np2 = __shfl_up(ip, o, 64);
        if (lane >= o) { ik += nk; ip += np2; }
    }
    float P = __shfl(ip, 63, 64);
    float k = ik - ck, pp = ip - cp;
    float acc = 0.f;
#pragma unroll
    for (int i = 0; i < 2; i++) {
        float cn = (float)hnv[i], cpp = (float)hpv[i];
        float c = cn + cpp;
        if (c > 0.f) {
            float Jb = (k > 0.f) ? (1.0f - (P - pp) / (P + k - pp)) : 0.0f;
            k += c; pp += cpp;
            float Ja = 1.0f - (P - pp) / (P + k - pp);
            int bn = NB - 1 - (lane * 2 + i);
            acc += ((float)bn + 0.5f) * (2.0f / NB) * (Ja - Jb);
        }
    }
    acc = wred(acc);

    if (lane == 0) {
        float np = fmaxf(r0, 1.0f);
        float v0 = fmaxf(r2 - r1 * r1 / np, 0.0f);
        float v1 = fmaxf(r4 - r3 * r3 / np, 0.0f);
        float valid, varl;
        if (p < 64) {
            varl = (v0 + v1) / (2.0f * np);
            valid = (c2 > 0.5f && c2 < 1.5f) ? 1.0f : 0.0f;
        } else {
            varl = v0 + v1;
            float gy = c0 - c3 * (1.0f / 256.0f);
            float gx = c1 - c4 * (1.0f / 256.0f);
            valid = (c2 > 0.5f && c2 < 1.5f &&
                     gy >= 0.0f && gy <= 1.0f && gx >= 0.0f && gx <= 1.0f) ? 1.0f : 0.0f;
        }
        float* po = ws + W_POUT + p * 4;
        po[0] = acc; po[1] = valid; po[2] = varl; po[3] = 0.0f;
    }
    __threadfence();
    unsigned old = 0;
    if (lane == 0) old = atomicAdd(cntr, 1u);
    old = (unsigned)__shfl((int)old, 0, 64);
    if (old != NPAIR - 1) return;
    __threadfence();   // acquire: see all blocks' stores

    volatile const float* pv = ws + W_POUT;
    volatile const float* sdv = ws + W_SEEDL;
    volatile const float* csv = ws + W_CSUM;
    for (int q = lane; q < NPAIR; q += 64) {
        fin[q * 4 + 0] = pv[q * 4 + 0];
        fin[q * 4 + 1] = pv[q * 4 + 1];
        fin[q * 4 + 2] = pv[q * 4 + 2];
        fin[q * 4 + 3] = sdv[q];
    }
    if (lane < 8) fin[NPAIR * 4 + lane] = csv[(lane * 2 + 0) * 41 + 40];
    __syncthreads();
    if (lane == 0) {
        double total = 0.0;
        for (int b = 0; b < 8; b++) {
            double s = 0.0, sl = 0.0;
            for (int jj2 = 0; jj2 < 8; jj2++) {
                int pr = b * 8 + jj2;
                double v = fin[pr * 4 + 1];
                s += v * ((double)fin[pr * 4 + 0] + 10.0 * (double)fin[pr * 4 + 2]);
                sl += v * (double)fin[pr * 4 + 3];
            }
            total += s + ((double)fin[NPAIR * 4 + b] + sl) / (double)HW;
        }
        for (int tt = 0; tt < 4; tt++) {
            double tl = 0.0, vl = 0.0, cnt = 0.0;
            for (int jj2 = 0; jj2 < 8; jj2++) {
                int pr = 64 + tt * 8 + jj2;
                double v = fin[pr * 4 + 1];
                tl += v * (double)fin[pr * 4 + 0];
                vl += v * (double)fin[pr * 4 + 2];
                cnt += v;
            }
            if (cnt < 1.0) cnt = 1.0;
            total += tl / cnt + 10.0 * vl / cnt;
        }
        *out = (float)total;
    }
}

// ---------------------------------------------------------------- launch
extern "C" void kernel_launch(void* const* d_in, const int* in_sizes, int n_in,
                              void* d_out, int out_size, void* d_ws, size_t ws_size,
                              hipStream_t stream)
{
    const float* segp = (const float*)d_in[0];   // [8,5,512,512] f32
    const float* trap = (const float*)d_in[1];   // [4,4,512,512] f32
    const int* inst   = (const int*)d_in[2];     // [8,512,512] i32
    // d_in[3] = labels: unused (label == (inst > 0) by construction)
    const int* cen    = (const int*)d_in[4];     // [8,512,512] i32 (bool)
    const float* off  = (const float*)d_in[5];   // [4,2,512,512] f32
    float* out = (float*)d_out;
    float* ws = (float*)d_ws;

    reduce_k<<<dim3(RB, 12, 2), 256, 0, stream>>>(segp, trap, inst, cen, off, ws);
    hist_k<<<dim3(RB, 12, 2), 256, 0, stream>>>(segp, trap, inst, ws);
    scanfin_k<<<NPAIR, 64, 0, stream>>>(ws, out);
}

// Round 7
// 64.831 us; speedup vs baseline: 5.5100x; 1.1467x over previous
//
#include <hip/hip_runtime.h>
#include <cstdint>
#include <cstddef>

#define HW (512 * 512)
#define NB 128
#define NPAIR 96
#define THRQ 4.9f            // > ln(128)=4.852: q>THRQ && !mask => bin 0 guaranteed
#define BSCALE 64.0f         // NB/2
#define RB 128               // blocks along x (2048 px/block)

// workspace float/word offsets
#define W_HNEG 0
#define W_HPOS (NPAIR * NB)                  // 12288
#define W_SEEDL (NPAIR * NB * 2)             // 24576
#define W_CNT (W_SEEDL + NPAIR)              // 24672
#define NZERO (W_CNT + 1)                    // 24673 words zeroed by reduce_k
#define W_PART 24704                         // part[12][81][RB]
#define W_CSUM (W_PART + 12 * 81 * RB)       // 149120, csum[12][81]
#define W_PRM (W_CSUM + 12 * 81)             // 150092, prm[12][8][4] (16B-aligned)
#define W_POUT (W_PRM + 12 * 32)             // 150476, pairout[96][4]

__device__ __forceinline__ float sigmoidf_(float x) {
    return 1.0f / (1.0f + __expf(-x));
}
__device__ __forceinline__ float tanhf_(float x) {
    float e = __expf(2.0f * x);
    return 1.0f - 2.0f / (e + 1.0f);
}
__device__ __forceinline__ float wred(float v) {
#pragma unroll
    for (int o = 32; o > 0; o >>= 1) v += __shfl_down(v, o, 64);
    return v;
}

// ---------------------------------------------------------------- pass 1: partial reductions (8 inst/block, single pass) + zero
// part[item][comp][bx]: 0..39 = j*5+{npx,ss0,ss0q,ss1,ss1q}; 40..79 = j*5+{cy,cx,cc,oy,ox}; 80 = seed bg
__global__ __launch_bounds__(256) void reduce_k(
    const float* __restrict__ segp, const float* __restrict__ trap,
    const int* __restrict__ inst, const int* __restrict__ cen,
    const float* __restrict__ off, float* __restrict__ ws)
{
    __shared__ float wavepart[4][41];
    __shared__ float centacc[40];
    int item = blockIdx.y;
    bool isseg = item < 8;
    int ii = isseg ? item : item - 8;
    int bx = blockIdx.x, tid = threadIdx.x;

    // cooperative zero of hneg/hpos/seedl/counter
    {
        int gb = (item * RB + bx) * 17 + tid;
        if (tid < 17 && gb < NZERO) ws[gb] = 0.0f;
    }
    if (tid < 40) centacc[tid] = 0.0f;
    __syncthreads();

    const float* pb = isseg ? segp + (size_t)item * 5 * HW
                            : trap + (size_t)ii * 4 * HW;
    const int* ib = inst + (size_t)ii * HW;
    const int* cb = cen + (size_t)ii * HW;
    const float* ob = off + (size_t)ii * 2 * HW;

    float npx[8], a0[8], q0[8], a1[8], q1[8];
#pragma unroll
    for (int j = 0; j < 8; j++) { npx[j]=0.f; a0[j]=0.f; q0[j]=0.f; a1[j]=0.f; q1[j]=0.f; }
    float sacc = 0.f;

    int base = bx * 2048;
#pragma unroll
    for (int it = 0; it < 2; ++it) {
        int idx = base + (it * 256 + tid) * 4;
        int4 v4 = *(const int4*)&ib[idx];
        const int vs[4] = { v4.x, v4.y, v4.z, v4.w };
        if (isseg) {
            float4 x4 = *(const float4*)&pb[4 * HW + idx];
            const float ss[4] = { x4.x, x4.y, x4.z, x4.w };
#pragma unroll
            for (int c = 0; c < 4; c++) {
                if (vs[c] == 0) { float sd = sigmoidf_(ss[c]); sacc += sd * sd; }
            }
        }
        if ((v4.x | v4.y | v4.z | v4.w) != 0) {
            int4 c4 = *(const int4*)&cb[idx];
            float4 x2 = *(const float4*)&pb[2 * HW + idx];
            float4 x3 = *(const float4*)&pb[3 * HW + idx];
            const int cs[4] = { c4.x, c4.y, c4.z, c4.w };
            const float s2s[4] = { x2.x, x2.y, x2.z, x2.w };
            const float s3s[4] = { x3.x, x3.y, x3.z, x3.w };
#pragma unroll
            for (int c = 0; c < 4; c++) {
                int v = vs[c];
                if (v == 0) continue;
                float s0 = sigmoidf_(s2s[c]);
                float s1 = sigmoidf_(s3s[c]);
                float s00 = s0 * s0, s11 = s1 * s1;
#pragma unroll
                for (int j = 0; j < 8; j++) {
                    float f = (v == j + 1) ? 1.0f : 0.0f;
                    npx[j] += f;
                    a0[j] += f * s0; q0[j] += f * s00;
                    a1[j] += f * s1; q1[j] += f * s11;
                }
                if (cs[c] != 0 && v >= 1 && v <= 8) {
                    int idxc = idx + c;
                    int cb5 = (v - 1) * 5;
                    int y = idxc >> 9, x = idxc & 511;
                    atomicAdd(&centacc[cb5 + 0], (float)y * (1.0f / 511.0f));
                    atomicAdd(&centacc[cb5 + 1], (float)x * (1.0f / 511.0f));
                    atomicAdd(&centacc[cb5 + 2], 1.0f);
                    if (!isseg) {
                        atomicAdd(&centacc[cb5 + 3], ob[idxc]);
                        atomicAdd(&centacc[cb5 + 4], ob[HW + idxc]);
                    }
                }
            }
        }
    }
    int lane = tid & 63, wave = tid >> 6;
#pragma unroll
    for (int j = 0; j < 8; j++) {
        float r0 = wred(npx[j]), r1 = wred(a0[j]), r2 = wred(q0[j]);
        float r3 = wred(a1[j]), r4 = wred(q1[j]);
        if (lane == 0) {
            wavepart[wave][j * 5 + 0] = r0; wavepart[wave][j * 5 + 1] = r1;
            wavepart[wave][j * 5 + 2] = r2; wavepart[wave][j * 5 + 3] = r3;
            wavepart[wave][j * 5 + 4] = r4;
        }
    }
    {
        float rs = wred(sacc);
        if (lane == 0) wavepart[wave][40] = rs;
    }
    __syncthreads();
    float* pit = ws + W_PART + (size_t)item * 81 * RB;
    if (tid < 40) {
        pit[tid * RB + bx] = wavepart[0][tid] + wavepart[1][tid] + wavepart[2][tid] + wavepart[3][tid];
    } else if (tid == 40) {
        pit[80 * RB + bx] = wavepart[0][40] + wavepart[1][40] + wavepart[2][40] + wavepart[3][40];
    } else if (tid < 81) {
        pit[(tid - 1) * RB + bx] = centacc[tid - 41];   // comps 40..79
    }
}

// ---------------------------------------------------------------- pass 2: per-item comp sums + MFMA-free param derivation
__global__ __launch_bounds__(256) void csum_k(float* __restrict__ ws)
{
    __shared__ float csh[81];
    int item = blockIdx.x, tid = threadIdx.x;
    bool isseg = item < 8;
    if (tid < 162) {
        int comp = tid >> 1;
        const float* p = ws + W_PART + (size_t)item * 81 * RB + comp * RB + (tid & 1) * 64;
        float s = 0.f;
#pragma unroll 8
        for (int i = 0; i < 64; i++) s += p[i];
        s += __shfl_xor(s, 1, 64);
        if ((tid & 1) == 0) csh[comp] = s;
    }
    __syncthreads();
    if (tid < 81) ws[W_CSUM + item * 81 + tid] = csh[tid];
    if (tid < 8) {
        int j = tid;
        float np = fmaxf(csh[j * 5], 1.0f);
        float cy = csh[40 + j * 5], cx = csh[40 + j * 5 + 1];
        if (!isseg) {
            cy -= csh[40 + j * 5 + 3] * (1.0f / 256.0f);
            cx -= csh[40 + j * 5 + 4] * (1.0f / 256.0f);
        }
        float* o = ws + W_PRM + item * 32 + j * 4;
        o[0] = cy;
        o[1] = cx;
        o[2] = __expf(10.0f * csh[j * 5 + 1] / np);
        o[3] = __expf(10.0f * csh[j * 5 + 3] / np);
    }
}

// ---------------------------------------------------------------- pass 3: LUT-culled histogram (8 inst/block, 1 pass)
__global__ __launch_bounds__(256) void hist_k(
    const float* __restrict__ segp, const float* __restrict__ trap,
    const int* __restrict__ inst, float* __restrict__ ws)
{
    __shared__ unsigned hh[8 * NB + 8];      // packed hist; tail 8 = seed sums (float)
    __shared__ float4 prmv[8];               // cy, cx, s0, s1
    __shared__ unsigned char lut[48 * 64];   // candidate bitmask over (e0,e1) cells
    int item = blockIdx.y;
    bool isseg = item < 8;
    int ii = isseg ? item : item - 8;
    int bx = blockIdx.x, tid = threadIdx.x;
    int pairBase = (isseg ? 0 : 64) + ii * 8;

    unsigned* wsu = (unsigned*)ws;
    unsigned* hneg = wsu + W_HNEG;
    unsigned* hpos = wsu + W_HPOS;
    float* seedl = ws + W_SEEDL;

    if (tid < 8) prmv[tid] = ((const float4*)(ws + W_PRM + item * 32))[tid];
    for (int i = tid; i < 8 * NB + 8; i += 256) hh[i] = 0u;
    __syncthreads();
    // build LUT: conservative min-q per cell vs THRQ
    for (int ci = tid; ci < 48 * 64; ci += 256) {
        int iy = ci >> 6, ix = ci & 63;
        float ey = -1.0f + ((float)iy + 0.5f) * (1.0f / 16.0f);
        float ex = -1.0f + ((float)ix + 0.5f) * (1.0f / 16.0f);
        unsigned mk = 0u;
#pragma unroll
        for (int j = 0; j < 8; j++) {
            float4 P = prmv[j];
            float dy = fmaxf(fabsf(ey - P.x) - (1.0f / 32.0f), 0.0f);
            float dx = fmaxf(fabsf(ex - P.y) - (1.0f / 32.0f), 0.0f);
            if (fmaf(dy * dy, P.z, dx * dx * P.w) <= THRQ) mk |= 1u << j;
        }
        lut[ci] = (unsigned char)mk;
    }
    __syncthreads();

    const float* pb = isseg ? segp + (size_t)item * 5 * HW
                            : trap + (size_t)ii * 4 * HW;
    const int* ib = inst + (size_t)ii * HW;

    int base = bx * 2048;
#pragma unroll
    for (int it = 0; it < 2; ++it) {
        int idx = base + (it * 256 + tid) * 4;
        int4 v4 = *(const int4*)&ib[idx];
        float4 f0 = *(const float4*)&pb[idx];
        float4 f1 = *(const float4*)&pb[HW + idx];
        const int vv[4] = { v4.x, v4.y, v4.z, v4.w };
        const float p0s[4] = { f0.x, f0.y, f0.z, f0.w };
        const float p1s[4] = { f1.x, f1.y, f1.z, f1.w };
#pragma unroll
        for (int c = 0; c < 4; c++) {
            int idxc = idx + c;
            int v = vv[c];
            int y = idxc >> 9, x = idxc & 511;
            float ym = (float)y * (1.0f / 511.0f);
            float xm = (float)x * (1.0f / 511.0f);
            float t0 = tanhf_(p0s[c]), t1 = tanhf_(p1s[c]);
            float e0 = isseg ? (t0 + ym) : (ym - t0);
            float e1 = isseg ? (t1 + xm) : (xm - t1);
            int iy = (int)((e0 + 1.0f) * 16.0f);
            int ix = (int)((e1 + 1.0f) * 16.0f);
            unsigned mask = lut[iy * 64 + ix];
            unsigned vb = (unsigned)(v - 1);
            if (vb < 8u) mask |= 1u << vb;
            while (mask) {
                int j = __ffs(mask) - 1;
                mask &= mask - 1u;
                float4 P = prmv[j];
                float d0 = e0 - P.x, d1 = e1 - P.y;
                float q = fmaf(d0 * d0, P.z, d1 * d1 * P.w);
                bool m = (v == j + 1);
                if (m || (q <= THRQ)) {
                    float dd = __expf(-q);
                    float e = m ? fmaf(-2.0f, dd, 2.0f) : 2.0f * dd;
                    int bin = (int)(e * BSCALE);
                    if (bin > NB - 1) bin = NB - 1;
                    atomicAdd(&hh[j * NB + bin], m ? 0x10000u : 1u);
                    if (m && isseg) {
                        float sd = sigmoidf_(pb[4 * HW + idxc]);
                        float df = sd - dd;
                        atomicAdd((float*)&hh[8 * NB + j], df * df);
                    }
                }
                // skipped (!m && q>THRQ): folded into bin0 by derivation below
            }
        }
    }
    __syncthreads();
    // derive bin-0 far-negatives: each pixel contributes exactly one hist add OR is far
    {
        int g = tid >> 5, gl = tid & 31;
        unsigned s = 0u;
#pragma unroll
        for (int b = 0; b < 4; b++) {
            unsigned hv = hh[g * NB + gl * 4 + b];
            s += (hv & 0xFFFFu) + (hv >> 16);
        }
#pragma unroll
        for (int o = 16; o > 0; o >>= 1) s += __shfl_down(s, o, 32);
        if (gl == 0) atomicAdd(&hh[g * NB], 2048u - s);
    }
    __syncthreads();
    // flush packed LDS hist -> global
    for (int i = tid; i < 8 * NB; i += 256) {
        unsigned hv = hh[i];
        if (hv) {
            int j = i >> 7, b = i & (NB - 1);
            size_t gb = (size_t)(pairBase + j) * NB + b;
            unsigned n = hv & 0xFFFFu, p = hv >> 16;
            if (n) atomicAdd(&hneg[gb], n);
            if (p) atomicAdd(&hpos[gb], p);
        }
    }
    if (isseg && tid < 8) {
        float sv = __uint_as_float(hh[8 * NB + tid]);
        if (sv != 0.0f) atomicAdd(&seedl[pairBase + tid], sv);
    }
}

// ---------------------------------------------------------------- pass 4: scan + per-pair params + counter-elected combine
__global__ __launch_bounds__(64) void scanfin_k(
    float* __restrict__ ws, float* __restrict__ out)
{
    __shared__ float fin[NPAIR * 4 + 8];
    int p = blockIdx.x;
    int lane = threadIdx.x;
    unsigned* wsu = (unsigned*)ws;
    const unsigned* hneg = wsu + W_HNEG;
    const unsigned* hpos = wsu + W_HPOS;
    unsigned* cntr = wsu + W_CNT;

    int item12 = (p < 64) ? (p >> 3) : (8 + ((p - 64) >> 3));
    int j = p & 7;
    const float* cs = ws + W_CSUM + item12 * 81;
    float val = 0.f;
    if (lane < 10) {
        int comp = (lane < 5) ? (j * 5 + lane) : (40 + j * 5 + (lane - 5));
        val = cs[comp];
    }
    float r0 = __shfl(val, 0, 64), r1 = __shfl(val, 1, 64), r2 = __shfl(val, 2, 64);
    float r3 = __shfl(val, 3, 64), r4 = __shfl(val, 4, 64);
    float c0 = __shfl(val, 5, 64), c1 = __shfl(val, 6, 64), c2 = __shfl(val, 7, 64);
    float c3 = __shfl(val, 8, 64), c4 = __shfl(val, 9, 64);

    // descending-bin lovasz scan (NB=128: 2 bins/lane)
    const unsigned* hn = hneg + (size_t)p * NB;
    const unsigned* hp = hpos + (size_t)p * NB;
    unsigned hnv[2], hpv[2];
    float ck = 0.f, cp = 0.f;
#pragma unroll
    for (int i = 0; i < 2; i++) {
        int bn = NB - 1 - (lane * 2 + i);
        unsigned a = hn[bn], b = hp[bn];
        hnv[i] = a; hpv[i] = b;
        ck += (float)(a + b); cp += (float)b;
    }
    float ik = ck, ip = cp;
#pragma unroll
    for (int o = 1; o < 64; o <<= 1) {
        float nk = __shfl_up(ik, o, 64), np2 = __shfl_up(ip, o, 64);
        if (lane >= o) { ik += nk; ip += np2; }
    }
    float P = __shfl(ip, 63, 64);
    float k = ik - ck, pp = ip - cp;
    float acc = 0.f;
#pragma unroll
    for (int i = 0; i < 2; i++) {
        float cn = (float)hnv[i], cpp = (float)hpv[i];
        float c = cn + cpp;
        if (c > 0.f) {
            float Jb = (k > 0.f) ? (1.0f - (P - pp) / (P + k - pp)) : 0.0f;
            k += c; pp += cpp;
            float Ja = 1.0f - (P - pp) / (P + k - pp);
            int bn = NB - 1 - (lane * 2 + i);
            acc += ((float)bn + 0.5f) * (2.0f / NB) * (Ja - Jb);
        }
    }
    acc = wred(acc);

    if (lane == 0) {
        float np = fmaxf(r0, 1.0f);
        float v0 = fmaxf(r2 - r1 * r1 / np, 0.0f);
        float v1 = fmaxf(r4 - r3 * r3 / np, 0.0f);
        float valid, varl;
        if (p < 64) {
            varl = (v0 + v1) / (2.0f * np);
            valid = (c2 > 0.5f && c2 < 1.5f) ? 1.0f : 0.0f;
        } else {
            varl = v0 + v1;
            float gy = c0 - c3 * (1.0f / 256.0f);
            float gx = c1 - c4 * (1.0f / 256.0f);
            valid = (c2 > 0.5f && c2 < 1.5f &&
                     gy >= 0.0f && gy <= 1.0f && gx >= 0.0f && gx <= 1.0f) ? 1.0f : 0.0f;
        }
        float* po = ws + W_POUT + p * 4;
        po[0] = acc; po[1] = valid; po[2] = varl; po[3] = 0.0f;
    }
    __threadfence();
    unsigned old = 0;
    if (lane == 0) old = atomicAdd(cntr, 1u);
    old = (unsigned)__shfl((int)old, 0, 64);
    if (old != NPAIR - 1) return;
    __threadfence();   // acquire: see all blocks' stores

    volatile const float* pv = ws + W_POUT;
    volatile const float* sdv = ws + W_SEEDL;
    volatile const float* csv = ws + W_CSUM;
    for (int q = lane; q < NPAIR; q += 64) {
        fin[q * 4 + 0] = pv[q * 4 + 0];
        fin[q * 4 + 1] = pv[q * 4 + 1];
        fin[q * 4 + 2] = pv[q * 4 + 2];
        fin[q * 4 + 3] = sdv[q];
    }
    if (lane < 8) fin[NPAIR * 4 + lane] = csv[lane * 81 + 80];
    __syncthreads();
    if (lane == 0) {
        double total = 0.0;
        for (int b = 0; b < 8; b++) {
            double s = 0.0, sl = 0.0;
            for (int jj = 0; jj < 8; jj++) {
                int pr = b * 8 + jj;
                double v = fin[pr * 4 + 1];
                s += v * ((double)fin[pr * 4 + 0] + 10.0 * (double)fin[pr * 4 + 2]);
                sl += v * (double)fin[pr * 4 + 3];
            }
            total += s + ((double)fin[NPAIR * 4 + b] + sl) / (double)HW;
        }
        for (int tt = 0; tt < 4; tt++) {
            double tl = 0.0, vl = 0.0, cnt = 0.0;
            for (int jj = 0; jj < 8; jj++) {
                int pr = 64 + tt * 8 + jj;
                double v = fin[pr * 4 + 1];
                tl += v * (double)fin[pr * 4 + 0];
                vl += v * (double)fin[pr * 4 + 2];
                cnt += v;
            }
            if (cnt < 1.0) cnt = 1.0;
            total += tl / cnt + 10.0 * vl / cnt;
        }
        *out = (float)total;
    }
}

// ---------------------------------------------------------------- launch
extern "C" void kernel_launch(void* const* d_in, const int* in_sizes, int n_in,
                              void* d_out, int out_size, void* d_ws, size_t ws_size,
                              hipStream_t stream)
{
    const float* segp = (const float*)d_in[0];   // [8,5,512,512] f32
    const float* trap = (const float*)d_in[1];   // [4,4,512,512] f32
    const int* inst   = (const int*)d_in[2];     // [8,512,512] i32
    // d_in[3] = labels: unused (label == (inst > 0) by construction)
    const int* cen    = (const int*)d_in[4];     // [8,512,512] i32 (bool)
    const float* off  = (const float*)d_in[5];   // [4,2,512,512] f32
    float* out = (float*)d_out;
    float* ws = (float*)d_ws;

    reduce_k<<<dim3(RB, 12), 256, 0, stream>>>(segp, trap, inst, cen, off, ws);
    csum_k<<<12, 256, 0, stream>>>(ws);
    hist_k<<<dim3(RB, 12), 256, 0, stream>>>(segp, trap, inst, ws);
    scanfin_k<<<NPAIR, 64, 0, stream>>>(ws, out);
}